// Round 9
// baseline (372.275 us; speedup 1.0000x reference)
//
#include <hip/hip_runtime.h>
#include <hip/hip_cooperative_groups.h>
#include <cmath>

namespace cg = cooperative_groups;

#define N_PTS 32768
#define HID   256
#define KTEST 1024
#define MB    32       // points per mlp chunk
#define RS    264      // padded H row stride (528 B = 33*16)
#define NBLK  (N_PTS / MB)      // 1024 chunks
#define CGRID 512               // cooperative blocks = 2/CU co-resident

typedef float  f32x4  __attribute__((ext_vector_type(4)));
typedef short  s16x4  __attribute__((ext_vector_type(4)));
typedef short  s16x8  __attribute__((ext_vector_type(8)));
typedef __bf16 bf16x8 __attribute__((ext_vector_type(8)));

__device__ __forceinline__ float b2f(unsigned short s) {
    return __uint_as_float(((unsigned int)s) << 16);
}
// native RNE fp32->bf16 (v_cvt_pk_bf16_f32 on gfx950)
__device__ __forceinline__ unsigned short cvt16(float x) {
    return __builtin_bit_cast(unsigned short, (__bf16)x);
}
// exact split for W: x = hi + lo_f (exact), lo = RNE16(lo_f)
__device__ __forceinline__ void split2(float x, unsigned short& hi, unsigned short& lo) {
    unsigned int b = __float_as_uint(x);
    hi = (unsigned short)(b >> 16);
    float hf = __uint_as_float(b & 0xFFFF0000u);
    lo = cvt16(x - hf);
}
__device__ __forceinline__ float fast_tanh(float z) {
    float e = __expf(2.0f * z);
    return 1.0f - 2.0f / (e + 1.0f);
}

// ---------------------------------------------------------------------------
// One vb-unit of the W conversion (R0/R3 fragment layout, UNSWAPPED mfma):
// vb = (z,kc,t): lane (q,ln) elem j holds W[kc*32+q*8+j][t*16+ln] as hi/lo.
// ---------------------------------------------------------------------------
__device__ __forceinline__ void wconv_unit(
    int vb, int lane,
    const float* __restrict__ W1r, const float* __restrict__ W2r,
    unsigned short* __restrict__ W1h, unsigned short* __restrict__ W1l,
    unsigned short* __restrict__ W2h, unsigned short* __restrict__ W2l)
{
    const int t = vb & 15, kc = (vb >> 4) & 7, z = vb >> 7;
    const float* W = z ? W2r : W1r;
    unsigned short* Wh = z ? W2h : W1h;
    unsigned short* Wl = z ? W2l : W1l;
    const int q = lane >> 4, ln = lane & 15;
    const int n = t * 16 + ln;
    const int kbase = kc * 32 + q * 8;

    s16x8 hv, lv;
    #pragma unroll
    for (int j = 0; j < 8; ++j) {
        unsigned short h, l;
        split2(W[(kbase + j) * HID + n], h, l);
        hv[j] = (short)h; lv[j] = (short)l;
    }
    const int out = ((t * 8 + kc) * 64 + lane) * 8;
    *(s16x8*)(Wh + out) = hv;
    *(s16x8*)(Wl + out) = lv;
}

// ---------------------------------------------------------------------------
// R3's PROVEN mlp body (58.9 us), verbatim: 16x16x32 MFMA unswapped, b64
// layer-0 LDS writes, fused sk partials -> coalesced partF row.
// R6 POST-MORTEM: operand-swap + setprio REVERTED (+3.1 us: VGPR 52->64,
// extra bias vec loads, setprio hurts barrier-lockstep loops).
// SQ_LDS_BANK_CONFLICT (~3.8M) is dominated by counted-but-free 2-way
// aliasing (m136) — NOT a usable signal for this kernel; stop chasing it.
// R4 POST-MORTEM: never bulk-accumulate via device atomics (coherence-point
// serialization, ~116 us).
// ---------------------------------------------------------------------------
__device__ __forceinline__ void mlp_body(
    const int cb, const int tid,
    unsigned short (* __restrict__ Hb)[MB][RS],
    float* __restrict__ sx_h, float* __restrict__ sx_l, float* __restrict__ sd,
    const float* __restrict__ x, const float* __restrict__ wq,
    const float* __restrict__ W0, const float* __restrict__ b0,
    const float* __restrict__ b1v, const float* __restrict__ b2v,
    const float* __restrict__ W3, const float* __restrict__ b3,
    const unsigned short* __restrict__ W1h, const unsigned short* __restrict__ W1l,
    const unsigned short* __restrict__ W2h, const unsigned short* __restrict__ W2l,
    float* __restrict__ u_arr, float* __restrict__ d_arr, float* __restrict__ partF)
{
    const int gp0 = cb * MB;

    // ---- layer 0 (1 -> 256): z'=W0[j], z''=0.  b64 LDS writes (4 cols).
    {
        const int m = tid & 31, seg = tid >> 5;   // 16 segs x 16 cols
        const float xm = x[gp0 + m];
        #pragma unroll
        for (int jb = 0; jb < 4; ++jb) {
            s16x4 vy, vyp, vypp;
            #pragma unroll
            for (int jl = 0; jl < 4; ++jl) {
                const int j = seg * 16 + jb * 4 + jl;
                float w = W0[j];
                float z = fmaf(xm, w, b0[j]);
                float y = fast_tanh(z);
                float s = 1.0f - y * y;
                float yp = s * w;
                float ypp = -2.0f * y * yp * w;
                vy[jl]   = (short)cvt16(y);
                vyp[jl]  = (short)cvt16(yp);
                vypp[jl] = (short)cvt16(ypp);
            }
            const int j0 = seg * 16 + jb * 4;
            *(s16x4*)&Hb[0][m][j0] = vy;
            *(s16x4*)&Hb[1][m][j0] = vyp;
            *(s16x4*)&Hb[2][m][j0] = vypp;
        }
    }
    __syncthreads();

    const int lane = tid & 63, wv = tid >> 6;      // wv 0..7
    const int q = lane >> 4, ln = lane & 15;

    // per-wave fragment base: tiles (wv*2, wv*2+1); offsets nt*4096 + kc*512
    const int fragbase = (wv * 2) * 8 * 512 + lane * 8;

    // ---- hidden layers 1,2 (256 -> 256)
    for (int layer = 0; layer < 2; ++layer) {
        const unsigned short* __restrict__ WhW = (layer ? W2h : W1h) + fragbase;
        const unsigned short* __restrict__ WlW = (layer ? W2l : W1l) + fragbase;
        const float* __restrict__ bb = layer ? b2v : b1v;

        f32x4 acc[3][2][2];   // [state][mfrag][ntile] = 48 AGPR
        #pragma unroll
        for (int s = 0; s < 3; ++s)
            #pragma unroll
            for (int mf = 0; mf < 2; ++mf)
                #pragma unroll
                for (int nt = 0; nt < 2; ++nt)
                    acc[s][mf][nt] = (f32x4){0.f, 0.f, 0.f, 0.f};

        s16x8 bh[2][2], bl[2][2];
        #pragma unroll
        for (int nt = 0; nt < 2; ++nt) {
            bh[0][nt] = *(const s16x8*)(WhW + nt * 4096);
            bl[0][nt] = *(const s16x8*)(WlW + nt * 4096);
        }

        int cur = 0;
        for (int kc = 0; kc < 8; ++kc) {
            const int nxt = cur ^ 1;
            if (kc < 7) {
                #pragma unroll
                for (int nt = 0; nt < 2; ++nt) {
                    const int off = nt * 4096 + (kc + 1) * 512;
                    bh[nxt][nt] = *(const s16x8*)(WhW + off);
                    bl[nxt][nt] = *(const s16x8*)(WlW + off);
                }
            }
            s16x8 av[3][2];
            #pragma unroll
            for (int s = 0; s < 3; ++s)
                #pragma unroll
                for (int mf = 0; mf < 2; ++mf)
                    av[s][mf] = *(const s16x8*)&Hb[s][mf * 16 + ln][kc * 32 + q * 8];
            #pragma unroll
            for (int s = 0; s < 3; ++s)
                #pragma unroll
                for (int mf = 0; mf < 2; ++mf)
                    #pragma unroll
                    for (int nt = 0; nt < 2; ++nt) {
                        acc[s][mf][nt] = __builtin_amdgcn_mfma_f32_16x16x32_bf16(
                            __builtin_bit_cast(bf16x8, av[s][mf]),
                            __builtin_bit_cast(bf16x8, bh[cur][nt]), acc[s][mf][nt], 0, 0, 0);
                        acc[s][mf][nt] = __builtin_amdgcn_mfma_f32_16x16x32_bf16(
                            __builtin_bit_cast(bf16x8, av[s][mf]),
                            __builtin_bit_cast(bf16x8, bl[cur][nt]), acc[s][mf][nt], 0, 0, 0);
                    }
            cur = nxt;
        }
        __syncthreads();   // all reads of old H done

        #pragma unroll
        for (int nt = 0; nt < 2; ++nt) {
            const int c = wv * 32 + nt * 16 + ln;
            const float bias = bb[c];
            #pragma unroll
            for (int mf = 0; mf < 2; ++mf) {
                #pragma unroll
                for (int i = 0; i < 4; ++i) {
                    const int r = mf * 16 + q * 4 + i;
                    float z   = acc[0][mf][nt][i] + bias;
                    float zp  = acc[1][mf][nt][i];
                    float zpp = acc[2][mf][nt][i];
                    float y  = fast_tanh(z);
                    float s  = 1.0f - y * y;
                    float yp = s * zp;
                    float ypp = fmaf(s, zpp, -2.0f * y * yp * zp);
                    Hb[0][r][c] = cvt16(y);
                    if (layer == 0) Hb[1][r][c] = cvt16(yp);  // last layer's h' never read
                    Hb[2][r][c] = cvt16(ypp);
                }
            }
        }
        __syncthreads();
    }

    // ---- final layer (256 -> 1); psum aliases Hb[1] (dead here)
    float* psum = (float*)&Hb[1][0][0];   // [2][16][32] floats = 4 KB
    {
        const int m = tid & 31, seg = tid >> 5;
        float su = 0.f, sx = 0.f;
        #pragma unroll
        for (int jj8 = 0; jj8 < 2; ++jj8) {
            const int j0 = seg * 16 + jj8 * 8;
            s16x8 vy = *(const s16x8*)&Hb[0][m][j0];
            s16x8 vx = *(const s16x8*)&Hb[2][m][j0];
            #pragma unroll
            for (int u = 0; u < 8; ++u) {
                float w3 = W3[j0 + u];
                su = fmaf(b2f((unsigned short)vy[u]), w3, su);
                sx = fmaf(b2f((unsigned short)vx[u]), w3, sx);
            }
        }
        psum[(0 * 16 + seg) * 32 + m] = su;
        psum[(1 * 16 + seg) * 32 + m] = sx;
    }
    __syncthreads();
    if (tid < MB) {
        float u = b3[0], uxx = 0.f;
        #pragma unroll
        for (int s2 = 0; s2 < 16; ++s2) {
            u   += psum[s2 * 32 + tid];
            uxx += psum[(16 + s2) * 32 + tid];
        }
        const int gp = gp0 + tid;
        u_arr[gp] = u;
        float xv = x[gp];
        float dv = -wq[gp] * (uxx + sinpif(xv));
        d_arr[gp] = dv;
        // stash for fused sk: exact 12-bit hi split (k*xh/2 exact, k<=1024)
        float xh = __uint_as_float(__float_as_uint(xv) & 0xFFFFF000u);
        sx_h[tid] = xh * 0.5f;
        sx_l[tid] = (xv - xh) * 0.5f;
        sd[tid]   = dv;
    }

    // ---- fused sk partial: thread handles k = tid+1 and tid+513 over the
    // chunk's 32 points. sin(pi*k*x) = v_sin(fract(fma(k, xl/2, fract(k*xh/2))))
    __syncthreads();
    {
        const float k1 = (float)(tid + 1);
        const float k2 = (float)(tid + 513);
        float s1 = 0.f, s2 = 0.f;
        #pragma unroll 8
        for (int i = 0; i < MB; ++i) {
            float xh = sx_h[i], xl = sx_l[i], dv = sd[i];
            float f1 = __builtin_amdgcn_fractf(k1 * xh);           // exact
            float t1 = __builtin_amdgcn_fractf(fmaf(k1, xl, f1));
            s1 = fmaf(__builtin_amdgcn_sinf(t1), dv, s1);
            float f2 = __builtin_amdgcn_fractf(k2 * xh);
            float t2 = __builtin_amdgcn_fractf(fmaf(k2, xl, f2));
            s2 = fmaf(__builtin_amdgcn_sinf(t2), dv, s2);
        }
        partF[cb * KTEST + tid]       = s1;   // coalesced row write
        partF[cb * KTEST + tid + 512] = s2;
    }
}

// ---------------------------------------------------------------------------
// SINGLE cooperative kernel: A) W conversion, B) 2 mlp chunks/block,
// C) reduce in blocks 0..31.  Replaces 3 dispatches (R6 post-mortem: ~72 us
// of every round's total is non-mlp — dominated by inter-dispatch overhead,
// not kernel work).  512 blocks x 512 thr = exactly 2 blocks/CU co-resident
// (LDS 2x50.7KB <= 160KB, ~100 unified regs = 4 waves/SIMD).
// ---------------------------------------------------------------------------
__global__ __launch_bounds__(512, 4) void fused_kernel(
    const float* __restrict__ x, const float* __restrict__ wq,
    const float* __restrict__ W0, const float* __restrict__ b0,
    const float* __restrict__ W1r, const float* __restrict__ b1v,
    const float* __restrict__ W2r, const float* __restrict__ b2v,
    const float* __restrict__ W3, const float* __restrict__ b3,
    unsigned short* __restrict__ W1h, unsigned short* __restrict__ W1l,
    unsigned short* __restrict__ W2h, unsigned short* __restrict__ W2l,
    float* __restrict__ u_arr, float* __restrict__ d_arr,
    float* __restrict__ partF, unsigned int* __restrict__ counter,
    float* __restrict__ red_g, float* __restrict__ out)
{
    __shared__ __align__(16) unsigned short Hb[3][MB][RS];   // 50688 B
    __shared__ float sx_h[MB], sx_l[MB], sd[MB];             // +384 B
    __shared__ int lastFlag;

    const int tid = threadIdx.x;
    const int bx = blockIdx.x;
    cg::grid_group grid = cg::this_grid();

    // ---- phase A: W conversion (same 256x64 shape as old wswz, spread
    // across blocks 0..255 so all CUs participate) + zero counter.
    if (bx < 256 && tid < 64)
        wconv_unit(bx, tid, W1r, W2r, W1h, W1l, W2h, W2l);
    if (bx == 0 && tid == 0) *counter = 0u;
    __threadfence();
    grid.sync();

    // ---- phase B: two point-chunks per block (R3-proven body, bit-exact)
    mlp_body(bx * 2 + 0, tid, Hb, sx_h, sx_l, sd, x, wq, W0, b0, b1v, b2v,
             W3, b3, W1h, W1l, W2h, W2l, u_arr, d_arr, partF);
    __syncthreads();
    mlp_body(bx * 2 + 1, tid, Hb, sx_h, sx_l, sd, x, wq, W0, b0, b1v, b2v,
             W3, b3, W1h, W1l, W2h, W2l, u_arr, d_arr, partF);
    __threadfence();
    grid.sync();

    // ---- phase C: blocks 0..31 column-reduce partF (512-thread variant of
    // the R3 reduce kernel); LDS partials alias dead Hb.
    if (bx >= 32) return;
    float* smC = (float*)&Hb[0][0][0];     // [16][33] floats = 2112 B

    const int kk = tid & 31;               // k within this block's 32-slice
    const int ch = tid >> 5;               // b-chunk 0..15 (64 b's each)
    const int k = bx * 32 + kk;

    const float* P = partF + (ch << 6) * KTEST + k;
    float s = 0.f;
    #pragma unroll 8
    for (int b = 0; b < 64; ++b) s += P[b << 10];
    smC[ch * 33 + kk] = s;
    __syncthreads();

    if (tid < 32) {
        float t = 0.f;
        #pragma unroll
        for (int j = 0; j < 16; ++j) t += smC[j * 33 + kk];
        float sq = t * t;
        #pragma unroll
        for (int off = 16; off > 0; off >>= 1) sq += __shfl_down(sq, off, 64);
        if (kk == 0) red_g[bx] = sq;
    }
    __threadfence();
    if (tid == 0)
        lastFlag = (atomicAdd(counter, 1u) == 31u);
    __syncthreads();
    if (!lastFlag) return;
    __threadfence();

    if (tid < 32) {
        float v = red_g[tid];
        #pragma unroll
        for (int off = 16; off > 0; off >>= 1) v += __shfl_down(v, off, 64);
        if (tid == 0) {
            out[0] = v * (1.0f / (float)KTEST);
            float u0 = u_arr[0], uN = u_arr[N_PTS - 1];
            out[1] = 5.0f * (u0 * u0 + uN * uN);
        }
    }
}

// ===========================================================================
// Fallback path (R3's proven 3-kernel pipeline, 131.4 us) — used only if the
// cooperative launch is rejected (occupancy/capture).
// ===========================================================================
__global__ __launch_bounds__(64) void wswz_kernel(
    const float* __restrict__ W1, const float* __restrict__ W2,
    unsigned short* __restrict__ Wh1, unsigned short* __restrict__ Wl1,
    unsigned short* __restrict__ Wh2, unsigned short* __restrict__ Wl2,
    unsigned int* __restrict__ counter)
{
    const int vb = (blockIdx.z << 7) | (blockIdx.y << 4) | blockIdx.x;
    wconv_unit(vb, threadIdx.x,
               W1, W2, Wh1, Wl1, Wh2, Wl2);
    if (threadIdx.x == 0 && vb == 0) *counter = 0u;
}

__global__ __launch_bounds__(512, 4) void mlp_kernel(
    const float* __restrict__ x, const float* __restrict__ wq,
    const float* __restrict__ W0, const float* __restrict__ b0,
    const float* __restrict__ b1v, const float* __restrict__ b2v,
    const float* __restrict__ W3, const float* __restrict__ b3,
    const unsigned short* __restrict__ W1h, const unsigned short* __restrict__ W1l,
    const unsigned short* __restrict__ W2h, const unsigned short* __restrict__ W2l,
    float* __restrict__ u_arr, float* __restrict__ d_arr,
    float* __restrict__ partF)
{
    __shared__ __align__(16) unsigned short Hb[3][MB][RS];
    __shared__ float sx_h[MB], sx_l[MB], sd[MB];
    mlp_body(blockIdx.x, threadIdx.x, Hb, sx_h, sx_l, sd, x, wq, W0, b0,
             b1v, b2v, W3, b3, W1h, W1l, W2h, W2l, u_arr, d_arr, partF);
}

__global__ __launch_bounds__(256) void reduce_kernel(
    const float* __restrict__ part, const float* __restrict__ u_arr,
    unsigned int* __restrict__ counter, float* __restrict__ red_g,
    float* __restrict__ out)
{
    __shared__ float sm[8][33];
    __shared__ int lastFlag;

    const int tid = threadIdx.x;
    const int kk = tid & 31;
    const int ch = tid >> 5;
    const int k = blockIdx.x * 32 + kk;

    const float* P = part + (ch << 7) * KTEST + k;
    float s = 0.f;
    #pragma unroll 8
    for (int b = 0; b < 128; ++b) s += P[b << 10];
    sm[ch][kk] = s;
    __syncthreads();

    if (tid < 32) {
        float t = 0.f;
        #pragma unroll
        for (int j = 0; j < 8; ++j) t += sm[j][kk];
        float sq = t * t;
        #pragma unroll
        for (int off = 16; off > 0; off >>= 1) sq += __shfl_down(sq, off, 64);
        if (kk == 0) red_g[blockIdx.x] = sq;
    }
    __threadfence();
    if (tid == 0)
        lastFlag = (atomicAdd(counter, 1u) == 31u);
    __syncthreads();
    if (!lastFlag) return;
    __threadfence();

    if (tid < 32) {
        float v = red_g[tid];
        #pragma unroll
        for (int off = 16; off > 0; off >>= 1) v += __shfl_down(v, off, 64);
        if (tid == 0) {
            out[0] = v * (1.0f / (float)KTEST);
            float u0 = u_arr[0], uN = u_arr[N_PTS - 1];
            out[1] = 5.0f * (u0 * u0 + uN * uN);
        }
    }
}

extern "C" void kernel_launch(void* const* d_in, const int* in_sizes, int n_in,
                              void* d_out, int out_size, void* d_ws, size_t ws_size,
                              hipStream_t stream)
{
    const float* x  = (const float*)d_in[0];
    const float* wq = (const float*)d_in[1];
    const float* W0 = (const float*)d_in[2];
    const float* b0 = (const float*)d_in[3];
    const float* W1 = (const float*)d_in[4];
    const float* b1 = (const float*)d_in[5];
    const float* W2 = (const float*)d_in[6];
    const float* b2 = (const float*)d_in[7];
    const float* W3 = (const float*)d_in[8];
    const float* b3 = (const float*)d_in[9];
    float* out = (float*)d_out;

    float* ws    = (float*)d_ws;
    float* u_arr = ws;                                   // 32768 f
    float* d_arr = ws + N_PTS;                           // 32768 f
    float* partF = ws + 2 * N_PTS;                       // 1024*1024 f = 4 MB
    float* red_g = ws + 2 * N_PTS + NBLK * KTEST;        // 32 f (+16 pad)
    unsigned int* counter = (unsigned int*)(red_g + 32);
    unsigned short* W1h = (unsigned short*)(red_g + 48); // 16B-aligned
    unsigned short* W1l = W1h + HID * HID;
    unsigned short* W2h = W1l + HID * HID;
    unsigned short* W2l = W2h + HID * HID;

    void* kargs[] = {
        (void*)&x, (void*)&wq, (void*)&W0, (void*)&b0, (void*)&W1, (void*)&b1,
        (void*)&W2, (void*)&b2, (void*)&W3, (void*)&b3,
        (void*)&W1h, (void*)&W1l, (void*)&W2h, (void*)&W2l,
        (void*)&u_arr, (void*)&d_arr, (void*)&partF, (void*)&counter,
        (void*)&red_g, (void*)&out
    };
    hipError_t err = hipLaunchCooperativeKernel(
        (const void*)fused_kernel, dim3(CGRID), dim3(512), kargs, 0, stream);

    if (err != hipSuccess) {
        (void)hipGetLastError();   // clear sticky error, run proven 3-kernel path
        wswz_kernel<<<dim3(16, 8, 2), 64, 0, stream>>>(W1, W2, W1h, W1l, W2h, W2l,
                                                       counter);
        mlp_kernel<<<NBLK, 512, 0, stream>>>(x, wq, W0, b0, b1, b2, W3, b3,
                                             W1h, W1l, W2h, W2l, u_arr, d_arr,
                                             partF);
        reduce_kernel<<<32, 256, 0, stream>>>(partF, u_arr, counter, red_g, out);
    }
}

// Round 10
// 131.259 us; speedup vs baseline: 2.8362x; 2.8362x over previous
//
#include <hip/hip_runtime.h>
#include <cmath>

#define N_PTS 32768
#define HID   256
#define KTEST 1024
#define MB    32       // points per mlp block
#define RS    264      // padded H row stride (528 B = 33*16)
#define SKC   256      // points per sk block (fallback path)
#define SKYB  (N_PTS / SKC)     // 128
#define SKGRID (4 * SKYB)       // 512 blocks total (fallback)
#define NBLK  (N_PTS / MB)      // 1024 mlp blocks

typedef float  f32x4  __attribute__((ext_vector_type(4)));
typedef short  s16x4  __attribute__((ext_vector_type(4)));
typedef short  s16x8  __attribute__((ext_vector_type(8)));
typedef __bf16 bf16x8 __attribute__((ext_vector_type(8)));

// SESSION LEDGER (counters-verified):
//  R4: 1M device atomics onto 512 lines = ~116 us coherence-point stall. NEVER.
//  R6: operand-swap + setprio = +3.1 us. SQ_LDS_BANK_CONFLICT is 2-way
//      counted-but-free noise here; not a usable signal.
//  R9: cooperative single-kernel = 4.7x stall on W reads (same-kernel dirty
//      L2 cross-XCD, no dispatch-boundary writeback). ALSO: total-kernel
//      overhead is a FIXED ~60-85 us envelope independent of dispatch count
//      (372-287.8=84 us with ONE dispatch) -> only device time matters.
//  => structure: R3's 3-kernel pipeline (proven 131.4), optimize mlp itself.

__device__ __forceinline__ float b2f(unsigned short s) {
    return __uint_as_float(((unsigned int)s) << 16);
}
// native RNE fp32->bf16 (v_cvt_pk_bf16_f32 on gfx950)
__device__ __forceinline__ unsigned short cvt16(float x) {
    return __builtin_bit_cast(unsigned short, (__bf16)x);
}
// exact split for W: x = hi + lo_f (exact), lo = RNE16(lo_f)
__device__ __forceinline__ void split2(float x, unsigned short& hi, unsigned short& lo) {
    unsigned int b = __float_as_uint(x);
    hi = (unsigned short)(b >> 16);
    float hf = __uint_as_float(b & 0xFFFF0000u);
    lo = cvt16(x - hf);
}
__device__ __forceinline__ float fast_tanh(float z) {
    float e = __expf(2.0f * z);
    return 1.0f - 2.0f / (e + 1.0f);
}

// ---------------------------------------------------------------------------
// W[k][n] fp32 -> hi/lo bf16 in 16x16x32 MFMA B-fragment order (R0/R3):
//   lane (q=lane>>4, ln=lane&15) elem j holds W[kc*32+q*8+j][t*16+ln];
//   elem offset = ((t*8+kc)*64+lane)*8.  Zeroes the done-counter.
// ---------------------------------------------------------------------------
__global__ __launch_bounds__(64) void wswz_kernel(
    const float* __restrict__ W1, const float* __restrict__ W2,
    unsigned short* __restrict__ Wh1, unsigned short* __restrict__ Wl1,
    unsigned short* __restrict__ Wh2, unsigned short* __restrict__ Wl2,
    unsigned int* __restrict__ counter)
{
    const int lane = threadIdx.x;      // 0..63
    const int t  = blockIdx.x;         // col tile 0..15
    const int kc = blockIdx.y;         // k chunk 0..7
    const float* W = blockIdx.z ? W2 : W1;
    unsigned short* Wh = blockIdx.z ? Wh2 : Wh1;
    unsigned short* Wl = blockIdx.z ? Wl2 : Wl1;
    const int q = lane >> 4, ln = lane & 15;
    const int n = t * 16 + ln;
    const int kbase = kc * 32 + q * 8;

    s16x8 hv, lv;
    #pragma unroll
    for (int j = 0; j < 8; ++j) {
        unsigned short h, l;
        split2(W[(kbase + j) * HID + n], h, l);
        hv[j] = (short)h; lv[j] = (short)l;
    }
    const int out = ((t * 8 + kc) * 64 + lane) * 8;
    *(s16x8*)(Wh + out) = hv;
    *(s16x8*)(Wl + out) = lv;

    if (lane == 0 && t == 0 && kc == 0 && blockIdx.z == 0)
        *counter = 0u;
}

// ---------------------------------------------------------------------------
// MLP fwd + u_xx (R3 body) + DISTANCE-2 W PREFETCH (R10 change):
// per kc the old distance-1 prefetch issued 8 b128 loads then ran 24 MFMA
// (~116 cyc) < ~200 cyc L2 latency -> ~84 cyc/iter under-coverage; real-VALU
// (VALUBusy-MfmaUtil ~16%) + MFMA 35% leaves ~49% both-pipes-idle.  3-buffer
// ring, fully unrolled so all ring indices are compile-time (runtime-indexed
// ext_vector arrays go to scratch).  Register budget: bh/bl 32->48 VGPR,
// ~68V + 48A = 116 <= 128 -> still 4 waves/SIMD.
// ---------------------------------------------------------------------------
__global__ __launch_bounds__(512, 4) void mlp_kernel(
    const float* __restrict__ x, const float* __restrict__ wq,
    const float* __restrict__ W0, const float* __restrict__ b0,
    const float* __restrict__ b1v, const float* __restrict__ b2v,
    const float* __restrict__ W3, const float* __restrict__ b3,
    const unsigned short* __restrict__ W1h, const unsigned short* __restrict__ W1l,
    const unsigned short* __restrict__ W2h, const unsigned short* __restrict__ W2l,
    float* __restrict__ u_arr, float* __restrict__ d_arr,
    float* __restrict__ partF)
{
    __shared__ __align__(16) unsigned short Hb[3][MB][RS];   // 50688 B
    __shared__ float sx_h[MB], sx_l[MB], sd[MB];             // +384 B

    const int tid = threadIdx.x;
    const int gp0 = blockIdx.x * MB;

    // ---- layer 0 (1 -> 256): z'=W0[j], z''=0.  b64 LDS writes (4 cols).
    {
        const int m = tid & 31, seg = tid >> 5;   // 16 segs x 16 cols
        const float xm = x[gp0 + m];
        #pragma unroll
        for (int jb = 0; jb < 4; ++jb) {
            s16x4 vy, vyp, vypp;
            #pragma unroll
            for (int jl = 0; jl < 4; ++jl) {
                const int j = seg * 16 + jb * 4 + jl;
                float w = W0[j];
                float z = fmaf(xm, w, b0[j]);
                float y = fast_tanh(z);
                float s = 1.0f - y * y;
                float yp = s * w;
                float ypp = -2.0f * y * yp * w;
                vy[jl]   = (short)cvt16(y);
                vyp[jl]  = (short)cvt16(yp);
                vypp[jl] = (short)cvt16(ypp);
            }
            const int j0 = seg * 16 + jb * 4;
            *(s16x4*)&Hb[0][m][j0] = vy;
            *(s16x4*)&Hb[1][m][j0] = vyp;
            *(s16x4*)&Hb[2][m][j0] = vypp;
        }
    }
    __syncthreads();

    const int lane = tid & 63, wv = tid >> 6;      // wv 0..7
    const int q = lane >> 4, ln = lane & 15;

    // per-wave fragment base: tiles (wv*2, wv*2+1); offsets nt*4096 + kc*512
    const int fragbase = (wv * 2) * 8 * 512 + lane * 8;

    // ---- hidden layers 1,2 (256 -> 256)
    for (int layer = 0; layer < 2; ++layer) {
        const unsigned short* __restrict__ WhW = (layer ? W2h : W1h) + fragbase;
        const unsigned short* __restrict__ WlW = (layer ? W2l : W1l) + fragbase;
        const float* __restrict__ bb = layer ? b2v : b1v;

        f32x4 acc[3][2][2];   // [state][mfrag][ntile] = 48 AGPR
        #pragma unroll
        for (int s = 0; s < 3; ++s)
            #pragma unroll
            for (int mf = 0; mf < 2; ++mf)
                #pragma unroll
                for (int nt = 0; nt < 2; ++nt)
                    acc[s][mf][nt] = (f32x4){0.f, 0.f, 0.f, 0.f};

        // 3-buffer ring, distance-2 prefetch
        s16x8 bh[3][2], bl[3][2];
        #pragma unroll
        for (int p = 0; p < 2; ++p)
            #pragma unroll
            for (int nt = 0; nt < 2; ++nt) {
                bh[p][nt] = *(const s16x8*)(WhW + nt * 4096 + p * 512);
                bl[p][nt] = *(const s16x8*)(WlW + nt * 4096 + p * 512);
            }

        #pragma unroll
        for (int kc = 0; kc < 8; ++kc) {
            const int cur = kc % 3;            // compile-time after unroll
            const int pre = (kc + 2) % 3;
            if (kc < 6) {
                #pragma unroll
                for (int nt = 0; nt < 2; ++nt) {
                    const int off = nt * 4096 + (kc + 2) * 512;
                    bh[pre][nt] = *(const s16x8*)(WhW + off);
                    bl[pre][nt] = *(const s16x8*)(WlW + off);
                }
            }
            s16x8 av[3][2];
            #pragma unroll
            for (int s = 0; s < 3; ++s)
                #pragma unroll
                for (int mf = 0; mf < 2; ++mf)
                    av[s][mf] = *(const s16x8*)&Hb[s][mf * 16 + ln][kc * 32 + q * 8];
            #pragma unroll
            for (int s = 0; s < 3; ++s)
                #pragma unroll
                for (int mf = 0; mf < 2; ++mf)
                    #pragma unroll
                    for (int nt = 0; nt < 2; ++nt) {
                        acc[s][mf][nt] = __builtin_amdgcn_mfma_f32_16x16x32_bf16(
                            __builtin_bit_cast(bf16x8, av[s][mf]),
                            __builtin_bit_cast(bf16x8, bh[cur][nt]), acc[s][mf][nt], 0, 0, 0);
                        acc[s][mf][nt] = __builtin_amdgcn_mfma_f32_16x16x32_bf16(
                            __builtin_bit_cast(bf16x8, av[s][mf]),
                            __builtin_bit_cast(bf16x8, bl[cur][nt]), acc[s][mf][nt], 0, 0, 0);
                    }
        }
        __syncthreads();   // all reads of old H done

        #pragma unroll
        for (int nt = 0; nt < 2; ++nt) {
            const int c = wv * 32 + nt * 16 + ln;
            const float bias = bb[c];
            #pragma unroll
            for (int mf = 0; mf < 2; ++mf) {
                #pragma unroll
                for (int i = 0; i < 4; ++i) {
                    const int r = mf * 16 + q * 4 + i;
                    float z   = acc[0][mf][nt][i] + bias;
                    float zp  = acc[1][mf][nt][i];
                    float zpp = acc[2][mf][nt][i];
                    float y  = fast_tanh(z);
                    float s  = 1.0f - y * y;
                    float yp = s * zp;
                    float ypp = fmaf(s, zpp, -2.0f * y * yp * zp);
                    Hb[0][r][c] = cvt16(y);
                    if (layer == 0) Hb[1][r][c] = cvt16(yp);  // last layer's h' never read
                    Hb[2][r][c] = cvt16(ypp);
                }
            }
        }
        __syncthreads();
    }

    // ---- final layer (256 -> 1); psum aliases Hb[1] (dead here)
    float* psum = (float*)&Hb[1][0][0];   // [2][16][32] floats = 4 KB
    {
        const int m = tid & 31, seg = tid >> 5;
        float su = 0.f, sx = 0.f;
        #pragma unroll
        for (int jj8 = 0; jj8 < 2; ++jj8) {
            const int j0 = seg * 16 + jj8 * 8;
            s16x8 vy = *(const s16x8*)&Hb[0][m][j0];
            s16x8 vx = *(const s16x8*)&Hb[2][m][j0];
            #pragma unroll
            for (int u = 0; u < 8; ++u) {
                float w3 = W3[j0 + u];
                su = fmaf(b2f((unsigned short)vy[u]), w3, su);
                sx = fmaf(b2f((unsigned short)vx[u]), w3, sx);
            }
        }
        psum[(0 * 16 + seg) * 32 + m] = su;
        psum[(1 * 16 + seg) * 32 + m] = sx;
    }
    __syncthreads();
    if (tid < MB) {
        float u = b3[0], uxx = 0.f;
        #pragma unroll
        for (int s2 = 0; s2 < 16; ++s2) {
            u   += psum[s2 * 32 + tid];
            uxx += psum[(16 + s2) * 32 + tid];
        }
        const int gp = gp0 + tid;
        u_arr[gp] = u;
        float xv = x[gp];
        float dv = -wq[gp] * (uxx + sinpif(xv));
        d_arr[gp] = dv;
        // stash for fused sk: exact 12-bit hi split (k*xh/2 exact, k<=1024)
        float xh = __uint_as_float(__float_as_uint(xv) & 0xFFFFF000u);
        sx_h[tid] = xh * 0.5f;
        sx_l[tid] = (xv - xh) * 0.5f;
        sd[tid]   = dv;
    }

    // ---- fused sk partial: thread handles k = tid+1 and tid+513 over the
    // block's 32 points. sin(pi*k*x) = v_sin(fract(fma(k, xl/2, fract(k*xh/2))))
    if (partF) {
        __syncthreads();
        const float k1 = (float)(tid + 1);
        const float k2 = (float)(tid + 513);
        float s1 = 0.f, s2 = 0.f;
        #pragma unroll 8
        for (int i = 0; i < MB; ++i) {
            float xh = sx_h[i], xl = sx_l[i], dv = sd[i];
            float f1 = __builtin_amdgcn_fractf(k1 * xh);           // exact
            float t1 = __builtin_amdgcn_fractf(fmaf(k1, xl, f1));
            s1 = fmaf(__builtin_amdgcn_sinf(t1), dv, s1);
            float f2 = __builtin_amdgcn_fractf(k2 * xh);
            float t2 = __builtin_amdgcn_fractf(fmaf(k2, xl, f2));
            s2 = fmaf(__builtin_amdgcn_sinf(t2), dv, s2);
        }
        partF[blockIdx.x * KTEST + tid]       = s1;   // coalesced row write
        partF[blockIdx.x * KTEST + tid + 512] = s2;
    }
}

// ---------------------------------------------------------------------------
// Column-reduce part[b][k] over b=0..1023 per k, square, mean; + boundary.
// R10: widened to 512 thr (16 chunks x 64 b) — halves per-thread serial
// load depth (128 -> 64 stride-4KB loads).  Lanes read contiguous 4B ->
// coalesced; LDS-combine 16 chunks/k; device-counter last block folds
// 32 block-partials + boundary loss.
// ---------------------------------------------------------------------------
__global__ __launch_bounds__(512) void reduce_kernel(
    const float* __restrict__ part, const float* __restrict__ u_arr,
    unsigned int* __restrict__ counter, float* __restrict__ red_g,
    float* __restrict__ out)
{
    __shared__ float sm[16][33];
    __shared__ int lastFlag;

    const int tid = threadIdx.x;
    const int kk = tid & 31;           // k within block
    const int ch = tid >> 5;           // b-chunk 0..15 (64 b's each)
    const int k = blockIdx.x * 32 + kk;

    const float* P = part + (ch << 6) * KTEST + k;
    float s = 0.f;
    #pragma unroll 8
    for (int b = 0; b < 64; ++b) s += P[b << 10];
    sm[ch][kk] = s;
    __syncthreads();

    if (tid < 32) {
        float t = 0.f;
        #pragma unroll
        for (int j = 0; j < 16; ++j) t += sm[j][kk];
        float sq = t * t;
        #pragma unroll
        for (int off = 16; off > 0; off >>= 1) sq += __shfl_down(sq, off, 64);
        if (kk == 0) red_g[blockIdx.x] = sq;
    }
    __threadfence();
    if (tid == 0)
        lastFlag = (atomicAdd(counter, 1u) == 31u);
    __syncthreads();
    if (!lastFlag) return;
    __threadfence();

    if (tid < 32) {
        float v = red_g[tid];
        #pragma unroll
        for (int off = 16; off > 0; off >>= 1) v += __shfl_down(v, off, 64);
        if (tid == 0) {
            out[0] = v * (1.0f / (float)KTEST);
            float u0 = u_arr[0], uN = u_arr[N_PTS - 1];
            out[1] = 5.0f * (u0 * u0 + uN * uN);
        }
    }
}

// ---------------------------------------------------------------------------
// Fallback sk + fused loss — used only if the workspace can't hold the 4 MB
// fused partial matrix.
// ---------------------------------------------------------------------------
__global__ __launch_bounds__(256) void sk_loss_kernel(
    const float* __restrict__ x, const float* __restrict__ d_arr,
    const float* __restrict__ u_arr, float* __restrict__ part,
    unsigned int* __restrict__ counter, float* __restrict__ out)
{
    __shared__ float xs_h[SKC], xs_l[SKC], ds[SKC];
    __shared__ float red[4];
    __shared__ int lastFlag;

    const int tid = threadIdx.x;
    const int k = blockIdx.x * 256 + tid;
    const int i0 = blockIdx.y * SKC;

    {
        float xv = x[i0 + tid];
        float xh = __uint_as_float(__float_as_uint(xv) & 0xFFFFF000u);
        xs_h[tid] = xh * 0.5f;
        xs_l[tid] = (xv - xh) * 0.5f;
        ds[tid]   = d_arr[i0 + tid];
    }
    __syncthreads();

    const float kf = (float)(k + 1);
    float s = 0.f;
    #pragma unroll 8
    for (int i = 0; i < SKC; ++i) {
        float A = kf * xs_h[i];
        float f = __builtin_amdgcn_fractf(A);
        float t = __builtin_amdgcn_fractf(fmaf(kf, xs_l[i], f));
        s = fmaf(__builtin_amdgcn_sinf(t), ds[i], s);
    }
    part[blockIdx.y * KTEST + k] = s;

    __threadfence();
    if (tid == 0)
        lastFlag = (atomicAdd(counter, 1u) == (unsigned)(SKGRID - 1));
    __syncthreads();
    if (!lastFlag) return;
    __threadfence();

    float a0 = 0.f, a1 = 0.f, a2 = 0.f, a3 = 0.f;
    const float* P = part + tid * 4;
    for (int yb = 0; yb < SKYB; ++yb) {
        f32x4 v = *(const f32x4*)(P + yb * KTEST);
        a0 += v[0]; a1 += v[1]; a2 += v[2]; a3 += v[3];
    }
    float sq = a0 * a0 + a1 * a1 + a2 * a2 + a3 * a3;
    #pragma unroll
    for (int off = 32; off > 0; off >>= 1) sq += __shfl_down(sq, off, 64);
    if ((tid & 63) == 0) red[tid >> 6] = sq;
    __syncthreads();
    if (tid == 0) {
        float t = red[0] + red[1] + red[2] + red[3];
        out[0] = t * (1.0f / (float)KTEST);
        float u0 = u_arr[0], uN = u_arr[N_PTS - 1];
        out[1] = 5.0f * (u0 * u0 + uN * uN);
    }
}

extern "C" void kernel_launch(void* const* d_in, const int* in_sizes, int n_in,
                              void* d_out, int out_size, void* d_ws, size_t ws_size,
                              hipStream_t stream)
{
    const float* x  = (const float*)d_in[0];
    const float* wq = (const float*)d_in[1];
    const float* W0 = (const float*)d_in[2];
    const float* b0 = (const float*)d_in[3];
    const float* W1 = (const float*)d_in[4];
    const float* b1 = (const float*)d_in[5];
    const float* W2 = (const float*)d_in[6];
    const float* b2 = (const float*)d_in[7];
    const float* W3 = (const float*)d_in[8];
    const float* b3 = (const float*)d_in[9];
    float* out = (float*)d_out;

    float* ws    = (float*)d_ws;
    float* u_arr = ws;                       // 32768 f
    float* d_arr = ws + N_PTS;               // 32768 f
    float* partS = ws + 2 * N_PTS;           // 128*1024 f (fallback)
    unsigned short* W1h = (unsigned short*)(ws + 2 * N_PTS + SKYB * KTEST);
    unsigned short* W1l = W1h + HID * HID;
    unsigned short* W2h = W1l + HID * HID;
    unsigned short* W2l = W2h + HID * HID;
    unsigned int* counter = (unsigned int*)(W2l + HID * HID);   // f-off 327680
    float* red_g = ws + 327696;              // 32 f
    float* partF = ws + 327744;              // 1024*1024 f = 4 MB
    const size_t need = (size_t)(327744 + NBLK * KTEST) * sizeof(float);
    const bool fused = ws_size >= need;

    wswz_kernel<<<dim3(16, 8, 2), 64, 0, stream>>>(W1, W2, W1h, W1l, W2h, W2l, counter);
    mlp_kernel<<<NBLK, 512, 0, stream>>>(x, wq, W0, b0, b1, b2, W3, b3,
                                         W1h, W1l, W2h, W2l, u_arr, d_arr,
                                         fused ? partF : nullptr);
    if (fused)
        reduce_kernel<<<32, 512, 0, stream>>>(partF, u_arr, counter, red_g, out);
    else
        sk_loss_kernel<<<dim3(4, SKYB), 256, 0, stream>>>(x, d_arr, u_arr, partS, counter, out);
}